// Round 4
// baseline (106.499 us; speedup 1.0000x reference)
//
#include <hip/hip_runtime.h>
#include <math.h>

#define DIM  4096          // 2^12 amplitudes
#define BLK  128           // 2 waves; 32 complex amplitudes per thread
#define NPAR 144           // 3 layers * 4 groups * 12 qubits

typedef float v2f __attribute__((ext_vector_type(2)));   // (re, im)

// ---- phase descriptors -----------------------------------------------------
// A phase holds a 5-bit register window: reg bit j <-> canonical bit (a+j)%12,
// wave bit (tid bit 6) <-> canonical bit wp, lane bit i (tid bits 0..5) <->
// canonical bit lp[i]. Lane placements chosen so the swizzled slot's bank-pair
// bits (slot[0..3] = c[0..3]^c[6..9]) contain 4 independent lane bits
// (verified per phase; U is the one 2-way exception).
struct Phase { int a; int wp; int lp[6]; };
constexpr Phase PH[9] = {
  {1, 11, {0,6,7,8,9,10}},   // 0 P : g0 RY c=1..5        (identical to X)
  {6, 11, {0,1,2,3,4,5}},    // 1 Q : g0 RY c=6..10
  {11,10, {4,5,6,7,8,9}},    // 2 R : g0 RY c=11,0 ; g1 CRX c=0..3
  {3, 10, {0,1,2,8,9,11}},   // 3 S : g1 CRX c=4..7
  {7, 0,  {1,2,3,4,5,6}},    // 4 T : g1 CRX c=8..11 ; g2 RY c=7..11
  {2, 0,  {1,7,8,9,10,11}},  // 5 U : g2 RY c=2..6
  {9, 4,  {2,3,5,6,7,8}},    // 6 V : g2 RY c=0,1 ; g3 i=0..3
  {5, 4,  {0,1,2,3,10,11}},  // 7 W2: g3 i=4..7
  {1, 11, {0,6,7,8,9,10}},   // 8 X : g3 i=8..11          (== P of next layer)
};

constexpr int swz(int c) { return c ^ ((c >> 6) & 63); }   // LDS slot swizzle

// byte-offset contribution of reg index r in phase pi (compile-time constant)
constexpr int regslot(int pi, int r) {
  int c = 0;
  for (int j = 0; j < 5; ++j)
    if ((r >> j) & 1) c |= 1 << ((PH[pi].a + j) % 12);
  return swz(c) * 8;
}

// byte-offset contribution of the thread's lane+wave bits (runtime, per phase)
template<int PI> __device__ __forceinline__ int lanebase(int tid) {
  int c = ((tid >> 6) & 1) << PH[PI].wp;
  #pragma unroll
  for (int i = 0; i < 6; ++i)
    c |= ((tid >> i) & 1) << PH[PI].lp[i];
  return swz(c) * 8;
}
// swz is GF(2)-linear and lane/reg fields are disjoint, so
// slot_bytes = lanebase ^ regslot.

// ---- LDS <-> register exchange --------------------------------------------
template<int PI> __device__ __forceinline__ void stash(v2f* buf, const v2f (&z)[32], int bb) {
  #pragma unroll
  for (int r = 0; r < 32; ++r)
    *(v2f*)((char*)buf + (bb ^ regslot(PI, r))) = z[r];
}
template<int PI> __device__ __forceinline__ void unstash(const v2f* buf, v2f (&z)[32], int bb) {
  #pragma unroll
  for (int r = 0; r < 32; ++r)
    z[r] = *(const v2f*)((const char*)buf + (bb ^ regslot(PI, r)));
}

// ---- gates on the 32-amplitude register file -------------------------------
// RY: r0' = c*a - s*b ; r1' = s*a + c*b   (validated R1-R3)
template<int J> __device__ __forceinline__ void ry32(v2f (&z)[32], float c, float s) {
  constexpr int M = 1 << J;
  #pragma unroll
  for (int p = 0; p < 16; ++p) {
    const int r0 = ((p & ~(M - 1)) << 1) | (p & (M - 1));
    const int r1 = r0 | M;
    v2f a = z[r0], bq = z[r1];
    z[r0] = c * a - s * bq;
    z[r1] = s * a + c * bq;
  }
}
// CRX (off-diagonal -i*s): r0'=(c*ar+s*bi, c*ai-s*br); r1'=(c*br+s*ai, c*bi-s*ar)
template<int JC, int JT> __device__ __forceinline__ void crx32(v2f (&z)[32], float c, float s) {
  constexpr int MC = 1 << JC, MT = 1 << JT;
  constexpr int mlo = MC < MT ? MC : MT;
  constexpr int mhi = MC < MT ? MT : MC;
  #pragma unroll
  for (int p = 0; p < 8; ++p) {
    int q = ((p & ~(mlo - 1)) << 1) | (p & (mlo - 1));
    q     = ((q & ~(mhi - 1)) << 1) | (q & (mhi - 1));
    const int r0 = q | MC;
    const int r1 = r0 | MT;
    v2f a = z[r0], bq = z[r1];
    v2f n0, n1;
    n0.x = c * a.x + s * bq.y;
    n0.y = c * a.y - s * bq.x;
    n1.x = c * bq.x + s * a.y;
    n1.y = c * bq.y - s * a.x;
    z[r0] = n0;
    z[r1] = n1;
  }
}

#define RYG(J, AO)       ry32<J>(z, cs_s[base + (AO)], sn_s[base + (AO)]);
#define CRXG(JC, JT, AO) crx32<JC, JT>(z, cs_s[base + (AO)], sn_s[base + (AO)]);

// wave-local restage: same wave bit in both phases -> this wave only touches
// its own canonical half of buf (disjoint from the other wave). One waitcnt,
// NO __syncthreads.
#define LOCALR(PO, PN) \
  stash<PO>(buf, z, bb); \
  asm volatile("s_waitcnt lgkmcnt(0)" ::: "memory"); \
  bb = lanebase<PN>(tid); \
  unstash<PN>(buf, z, bb);

// cross-wave restage: wave bit moves -> full-block exchange, 2 barriers.
#define BARRR(PO, PN) \
  __syncthreads(); \
  stash<PO>(buf, z, bb); \
  __syncthreads(); \
  bb = lanebase<PN>(tid); \
  unstash<PN>(buf, z, bb);

__global__ __launch_bounds__(BLK) void ansatz_kernel(
    const float* __restrict__ sre, const float* __restrict__ sim,
    const float* __restrict__ params, float* __restrict__ out) {

  __shared__ v2f   buf[DIM];            // 32 KB swizzled canonical state
  __shared__ float cs_s[NPAR], sn_s[NPAR];

  const int b = blockIdx.x, tid = threadIdx.x;

  for (int i = tid; i < DIM; i += BLK)
    buf[swz(i)] = (v2f){ sre[b * DIM + i], sim[b * DIM + i] };
  for (int i = tid; i < NPAR; i += BLK) {
    float s, c;
    sincosf(0.5f * params[b * NPAR + i], &s, &c);
    cs_s[i] = c; sn_s[i] = s;
  }
  __syncthreads();

  v2f z[32];
  int bb = lanebase<0>(tid);
  unstash<0>(buf, z, bb);

  for (int l = 0; l < 3; ++l) {
    const int base = 48 * l;
    // P: g0 RY on c=1..5  (angle = 11-c)
    RYG(0,10) RYG(1,9) RYG(2,8) RYG(3,7) RYG(4,6)
    LOCALR(0, 1)
    // Q: g0 RY on c=6..10
    RYG(0,5) RYG(1,4) RYG(2,3) RYG(3,2) RYG(4,1)
    BARRR(1, 2)
    // R: g0 RY on c=11 (j0), c=0 (j1); g1 CRX ctrl c=0..3 (angle 12+c)
    RYG(0,0) RYG(1,11)
    CRXG(1,0,12) CRXG(2,1,13) CRXG(3,2,14) CRXG(4,3,15)
    LOCALR(2, 3)
    // S: g1 CRX ctrl c=4..7
    CRXG(1,0,16) CRXG(2,1,17) CRXG(3,2,18) CRXG(4,3,19)
    BARRR(3, 4)
    // T: g1 CRX ctrl c=8..11; then g2 RY on c=7..11 (angle 24+(11-c))
    CRXG(1,0,20) CRXG(2,1,21) CRXG(3,2,22) CRXG(4,3,23)
    RYG(0,28) RYG(1,27) RYG(2,26) RYG(3,25) RYG(4,24)
    LOCALR(4, 5)
    // U: g2 RY on c=2..6
    RYG(0,33) RYG(1,32) RYG(2,31) RYG(3,30) RYG(4,29)
    BARRR(5, 6)
    // V: g2 RY on c=0 (j3), c=1 (j4); g3 i=0..3 (ctrl 0,11,10,9; angle 36+i)
    RYG(3,35) RYG(4,34)
    CRXG(3,4,36) CRXG(2,3,37) CRXG(1,2,38) CRXG(0,1,39)
    LOCALR(6, 7)
    // W2: g3 i=4..7 (ctrl 8,7,6,5)
    CRXG(3,4,40) CRXG(2,3,41) CRXG(1,2,42) CRXG(0,1,43)
    BARRR(7, 8)
    // X: g3 i=8..11 (ctrl 4,3,2,1). X layout == P layout: next layer's P
    // gates continue in-register with no restage.
    CRXG(3,4,44) CRXG(2,3,45) CRXG(1,2,46) CRXG(0,1,47)
  }

  // final: X-layout regs -> swizzled canonical LDS -> coalesced global store
  __syncthreads();
  stash<8>(buf, z, bb);
  __syncthreads();
  v2f* out2 = (v2f*)out + (size_t)b * DIM;
  for (int i = tid; i < DIM; i += BLK)
    out2[i] = buf[swz(i)];
}

extern "C" void kernel_launch(void* const* d_in, const int* in_sizes, int n_in,
                              void* d_out, int out_size, void* d_ws, size_t ws_size,
                              hipStream_t stream) {
  const float* sre    = (const float*)d_in[0];
  const float* sim    = (const float*)d_in[1];
  const float* params = (const float*)d_in[2];
  float* out          = (float*)d_out;

  const int B = in_sizes[0] / DIM;   // 128
  ansatz_kernel<<<B, BLK, 0, stream>>>(sre, sim, params, out);
}

// Round 5
// 90.668 us; speedup vs baseline: 1.1746x; 1.1746x over previous
//
#include <hip/hip_runtime.h>
#include <math.h>

#define DIM  4096
#define BLK  256            // 4 waves; 16 amplitudes (v2f) per thread
#define NPAR 144

typedef float v2f __attribute__((ext_vector_type(2)));

// ---------------------------------------------------------------------------
// Phase system: each of 36 epochs assigns the 12 canonical state bits to
// roles: 4 register bits (reg[j] = canonical bit of reg bit j), 2 wave bits
// (tid bits 6,7), 6 lane bits (tid bits 0..5, sorted ascending canonical).
// Gates in an epoch act only on register-local bits (CRX control may not be
// a wave bit in this schedule). Between epochs: restage through LDS.
// Wave bits are pinned across runs of epochs -> those restages are
// wave-local (private LDS quarter, no __syncthreads).
// ---------------------------------------------------------------------------
struct Ph { int reg[4]; int wav[2]; };
struct TMap { unsigned pk[8]; unsigned short so[16]; unsigned short rn[16]; };

constexpr int REGS[12][4] = {
  {8,9,10,11},   // e0 : RY0 8,9,10,11
  {4,5,6,7},     // e1 : RY0 4..7
  {0,1,2,3},     // e2 : RY0 0..3
  {0,1,2,11},    // e3 : g1 C(0,11) C(1,0) C(2,1)
  {2,3,4,5},     // e4 : g1 C(3,2) C(4,3) C(5,4)
  {5,6,7,8},     // e5 : g1 C(6,5) C(7,6) C(8,7)
  {8,9,10,11},   // e6 : g1 C(9,8) C(10,9) C(11,10) + RY2 8,9
  {4,5,6,7},     // e7 : RY2 4..7
  {0,1,10,11},   // e8 : RY2 10,11,0,1 + g3 C(0,1) C(11,0) C(10,11)
  {7,8,9,10},    // e9 : g3 C(9,10) C(8,9) C(7,8)
  {4,5,6,7},     // e10: g3 C(6,7) C(5,6) C(4,5)
  {1,2,3,4}      // e11: RY2 2,3 + g3 C(3,4) C(2,3) C(1,2)
};

constexpr Ph mkPh(int idx) {            // idx 0..35 (layer*12 + epoch)
  int l = idx / 12, e = idx % 12;
  Ph p = {};
  for (int j = 0; j < 4; ++j) p.reg[j] = REGS[e][j];
  int w0, w1;
  if (e == 11 || (l > 0 && e == 0)) { w0 = 0; w1 = 5; }
  else if (l == 0 && e <= 1)        { w0 = 0; w1 = 1; }
  else if (e <= 5)                  { w0 = 9; w1 = 10; }
  else                              { w0 = 2; w1 = 3; }
  p.wav[0] = w0; p.wav[1] = w1;
  return p;
}
// i = 0..37: 0 and 37 are the GLOBAL pseudo-phase (regs = c0..3 -> the 16
// consecutive amplitudes a thread owns in global layout; wave = c10,c11).
constexpr Ph phaseAt(int i) {
  if (i == 0 || i == 37) { Ph p = {{0,1,2,3},{10,11}}; return p; }
  return mkPh(i - 1);
}
constexpr bool inArr(const int* a, int n, int b) {
  for (int i = 0; i < n; ++i) if (a[i] == b) return true;
  return false;
}
constexpr bool isLoc(int t) {
  if (t == 0 || t == 36) return false;
  Ph a = phaseAt(t), b = phaseAt(t + 1);
  return a.wav[0] == b.wav[0] && a.wav[1] == b.wav[1];
}
constexpr int bufIdx(int t) {           // alternating cross buffer (init -> 0)
  int k = 0;
  for (int u = 0; u <= t; ++u) if (!isLoc(u)) ++k;
  return (k + 1) & 1;
}

struct BuildOut { TMap m; bool ok; };

// Build the GF(2)-linear canonical->slot map for transition old->new.
// Slot bits 0..3 (bank-pair bits of an 8B access) are constructed from lane
// bits of BOTH phases (common singles, then XOR pairs a(old-lane)^b(new-lane))
// -> every stash and unstash is bank-conflict-free. Remaining bits get
// identity rows; for local transitions the wave bits sit at slot bits 10,11
// -> each wave's data stays in its private 8KB region.
constexpr BuildOut buildT(Ph o, Ph n, bool local) {
  BuildOut R = {};
  R.ok = true;
  bool lo[12] = {}, ln[12] = {};
  for (int b = 0; b < 12; ++b) {
    lo[b] = !inArr(o.reg, 4, b) && !inArr(o.wav, 2, b);
    ln[b] = !inArr(n.reg, 4, b) && !inArr(n.wav, 2, b);
  }
  int col[12] = {};
  bool uo[12] = {}, un[12] = {}, inBank[12] = {}, pairA[12] = {};
  int row = 0;
  for (int b = 0; b < 12 && row < 4; ++b)
    if (lo[b] && ln[b]) { col[b] |= 1 << row; uo[b] = un[b] = true; inBank[b] = true; ++row; }
  while (row < 4) {
    int a = -1, c = -1;
    for (int b = 0; b < 12; ++b) if (lo[b] && !uo[b]) { a = b; break; }
    for (int b = 0; b < 12; ++b) if (ln[b] && !un[b]) { c = b; break; }
    if (a < 0 || c < 0) { R.ok = false; return R; }
    col[a] |= 1 << row; col[c] |= 1 << row;
    uo[a] = true; un[c] = true; inBank[a] = true; inBank[c] = true; pairA[a] = true;
    ++row;
  }
  bool idset[12] = {};
  int nid = 0;
  for (int b = 0; b < 12; ++b) { idset[b] = !inBank[b] || pairA[b]; if (idset[b]) ++nid; }
  if (nid != 8) { R.ok = false; return R; }
  if (local) {
    if (!idset[o.wav[0]] || !idset[o.wav[1]]) { R.ok = false; return R; }
    col[o.wav[0]] |= 1 << 10; col[o.wav[1]] |= 1 << 11;
    idset[o.wav[0]] = idset[o.wav[1]] = false;
    int rr = 4;
    for (int b = 0; b < 12; ++b) if (idset[b]) { col[b] |= 1 << rr; ++rr; }
    if (rr != 10) { R.ok = false; return R; }
  } else {
    int rr = 4;
    for (int b = 0; b < 12; ++b) if (idset[b]) { col[b] |= 1 << rr; ++rr; }
    if (rr != 12) { R.ok = false; return R; }
  }
  // invertibility (rank-12) via GF(2) basis
  {
    int pv[12] = {}, pb[12] = {};
    int nr = 0;
    for (int b = 0; b < 12; ++b) {
      int v = col[b];
      for (int k = 0; k < nr; ++k) if (v & pb[k]) v ^= pv[k];
      if (v) { pb[nr] = v & (-v); pv[nr] = v; ++nr; }
    }
    if (nr != 12) { R.ok = false; return R; }
  }
  int Lo[6] = {}, Ln[6] = {};
  int i0 = 0, i1 = 0;
  for (int b = 0; b < 12; ++b) { if (lo[b]) Lo[i0++] = b; if (ln[b]) Ln[i1++] = b; }
  for (int i = 0; i < 8; ++i) {
    unsigned po = (i < 6) ? (unsigned)col[Lo[i]] : (unsigned)col[o.wav[i - 6]];
    unsigned pn = (i < 6) ? (unsigned)col[Ln[i]] : (unsigned)col[n.wav[i - 6]];
    R.m.pk[i] = po | (pn << 16);
  }
  for (int r = 0; r < 16; ++r) {
    int s = 0, t = 0;
    for (int j = 0; j < 4; ++j)
      if ((r >> j) & 1) { s ^= col[o.reg[j]]; t ^= col[n.reg[j]]; }
    R.m.so[r] = (unsigned short)(s * 8);
    R.m.rn[r] = (unsigned short)(t * 8);
  }
  return R;
}

struct AllT { TMap t[37]; bool loc[37]; int buf[37]; bool ok; };
constexpr AllT buildAll() {
  AllT A = {};
  A.ok = true;
  for (int t = 0; t < 37; ++t) {
    BuildOut b = buildT(phaseAt(t), phaseAt(t + 1), isLoc(t));
    A.t[t] = b.m;
    A.ok = A.ok && b.ok;
    A.loc[t] = isLoc(t);
    A.buf[t] = bufIdx(t);
  }
  return A;
}
constexpr AllT AT = buildAll();
static_assert(AT.ok, "slot-map construction failed");

// ---------------- gates on the 16-amplitude register file -------------------
template<int J>
__device__ __forceinline__ void ry16(v2f (&z)[16], v2f a) {
  const float c = a.x, s = a.y;
  #pragma unroll
  for (int p = 0; p < 8; ++p) {
    const int r0 = ((p & ~((1 << J) - 1)) << 1) | (p & ((1 << J) - 1));
    const int r1 = r0 | (1 << J);
    v2f u = z[r0], v = z[r1];
    z[r0] = c * u - s * v;
    z[r1] = s * u + c * v;
  }
}
// CRX, off-diagonal -i*s (validated R1-R4)
template<int JC, int JT>
__device__ __forceinline__ void crx16(v2f (&z)[16], v2f a) {
  const float c = a.x, s = a.y;
  constexpr int MC = 1 << JC, MT = 1 << JT;
  constexpr int mlo = MC < MT ? MC : MT;
  constexpr int mhi = MC < MT ? MT : MC;
  #pragma unroll
  for (int p = 0; p < 4; ++p) {
    int q = ((p & ~(mlo - 1)) << 1) | (p & (mlo - 1));
    q = ((q & ~(mhi - 1)) << 1) | (q & (mhi - 1));
    const int r0 = q | MC, r1 = r0 | MT;
    v2f u = z[r0], v = z[r1];
    v2f n0, n1;
    n0.x = c * u.x + s * v.y;
    n0.y = c * u.y - s * v.x;
    n1.x = c * v.x + s * u.y;
    n1.y = c * v.y - s * u.x;
    z[r0] = n0; z[r1] = n1;
  }
}

template<int E>
__device__ __forceinline__ void gates(v2f (&z)[16], const v2f* ang, int base) {
  auto A = [&](int k) { return ang[base + k]; };
  if constexpr (E == 0)      { ry16<0>(z,A(3));  ry16<1>(z,A(2));  ry16<2>(z,A(1));  ry16<3>(z,A(0)); }
  else if constexpr (E == 1) { ry16<0>(z,A(7));  ry16<1>(z,A(6));  ry16<2>(z,A(5));  ry16<3>(z,A(4)); }
  else if constexpr (E == 2) { ry16<0>(z,A(11)); ry16<1>(z,A(10)); ry16<2>(z,A(9));  ry16<3>(z,A(8)); }
  else if constexpr (E == 3) { crx16<0,3>(z,A(12)); crx16<1,0>(z,A(13)); crx16<2,1>(z,A(14)); }
  else if constexpr (E == 4) { crx16<1,0>(z,A(15)); crx16<2,1>(z,A(16)); crx16<3,2>(z,A(17)); }
  else if constexpr (E == 5) { crx16<1,0>(z,A(18)); crx16<2,1>(z,A(19)); crx16<3,2>(z,A(20)); }
  else if constexpr (E == 6) { crx16<1,0>(z,A(21)); crx16<2,1>(z,A(22)); crx16<3,2>(z,A(23));
                               ry16<0>(z,A(27)); ry16<1>(z,A(26)); }
  else if constexpr (E == 7) { ry16<0>(z,A(31)); ry16<1>(z,A(30)); ry16<2>(z,A(29)); ry16<3>(z,A(28)); }
  else if constexpr (E == 8) { ry16<2>(z,A(25)); ry16<3>(z,A(24)); ry16<0>(z,A(35)); ry16<1>(z,A(34));
                               crx16<0,1>(z,A(36)); crx16<3,0>(z,A(37)); crx16<2,3>(z,A(38)); }
  else if constexpr (E == 9) { crx16<2,3>(z,A(39)); crx16<1,2>(z,A(40)); crx16<0,1>(z,A(41)); }
  else if constexpr (E == 10){ crx16<2,3>(z,A(42)); crx16<1,2>(z,A(43)); crx16<0,1>(z,A(44)); }
  else                       { ry16<1>(z,A(33)); ry16<2>(z,A(32));
                               crx16<2,3>(z,A(45)); crx16<1,2>(z,A(46)); crx16<0,1>(z,A(47)); }
}

template<int T>
__device__ __forceinline__ void restage(v2f (&z)[16], int tid, char* Lb, char* C0, char* C1) {
  constexpr bool LOC = AT.loc[T];
  char* buf = LOC ? Lb : (AT.buf[T] ? C1 : C0);
  unsigned acc = 0;
  #pragma unroll
  for (int i = 0; i < 8; ++i)
    acc ^= (unsigned)(-((tid >> i) & 1)) & AT.t[T].pk[i];
  const unsigned bo = (acc & 0xfffu) << 3;
  const unsigned bn = ((acc >> 16) & 0xfffu) << 3;
  #pragma unroll
  for (int r = 0; r < 16; ++r)
    *(v2f*)(buf + (bo ^ AT.t[T].so[r])) = z[r];
  if (LOC) { asm volatile("s_waitcnt lgkmcnt(0)" ::: "memory"); }
  else     { __syncthreads(); }
  #pragma unroll
  for (int r = 0; r < 16; ++r)
    z[r] = *(const v2f*)(buf + (bn ^ AT.t[T].rn[r]));
}

template<int L>
__device__ __forceinline__ void layer(v2f (&z)[16], int tid, const v2f* ang,
                                      char* Lb, char* C0, char* C1) {
  const int base = 48 * L;
  gates<0>(z, ang, base);  restage<12*L + 1>(z, tid, Lb, C0, C1);
  gates<1>(z, ang, base);  restage<12*L + 2>(z, tid, Lb, C0, C1);
  gates<2>(z, ang, base);  restage<12*L + 3>(z, tid, Lb, C0, C1);
  gates<3>(z, ang, base);  restage<12*L + 4>(z, tid, Lb, C0, C1);
  gates<4>(z, ang, base);  restage<12*L + 5>(z, tid, Lb, C0, C1);
  gates<5>(z, ang, base);  restage<12*L + 6>(z, tid, Lb, C0, C1);
  gates<6>(z, ang, base);  restage<12*L + 7>(z, tid, Lb, C0, C1);
  gates<7>(z, ang, base);  restage<12*L + 8>(z, tid, Lb, C0, C1);
  gates<8>(z, ang, base);  restage<12*L + 9>(z, tid, Lb, C0, C1);
  gates<9>(z, ang, base);  restage<12*L + 10>(z, tid, Lb, C0, C1);
  gates<10>(z, ang, base); restage<12*L + 11>(z, tid, Lb, C0, C1);
  gates<11>(z, ang, base);
  if constexpr (L < 2) restage<12*L + 12>(z, tid, Lb, C0, C1);
}

__global__ __launch_bounds__(BLK) void ansatz_kernel(
    const float* __restrict__ sre, const float* __restrict__ sim,
    const float* __restrict__ params, float* __restrict__ out) {

  __shared__ v2f C0s[DIM], C1s[DIM], Ls[DIM];   // 3 x 32 KB
  __shared__ v2f ang[NPAR];

  const int b = blockIdx.x, tid = threadIdx.x;
  char* C0 = (char*)C0s;
  char* C1 = (char*)C1s;
  char* Lb = (char*)Ls;

  if (tid < NPAR) {
    float s, c;
    sincosf(0.5f * params[b * NPAR + tid], &s, &c);
    v2f a; a.x = c; a.y = s;
    ang[tid] = a;
  }

  v2f z[16];
  // ---- init: coalesced float4 global loads -> stash into C0 (T=0) ----
  {
    const float4* pr = (const float4*)(sre + b * DIM + (tid << 4));
    const float4* pi = (const float4*)(sim + b * DIM + (tid << 4));
    float4 fr[4], fi[4];
    #pragma unroll
    for (int k = 0; k < 4; ++k) { fr[k] = pr[k]; fi[k] = pi[k]; }
    unsigned acc = 0;
    #pragma unroll
    for (int i = 0; i < 8; ++i)
      acc ^= (unsigned)(-((tid >> i) & 1)) & AT.t[0].pk[i];
    const unsigned bo = (acc & 0xfffu) << 3;
    const unsigned bn = ((acc >> 16) & 0xfffu) << 3;
    #pragma unroll
    for (int r = 0; r < 16; ++r) {
      const float* f0 = (const float*)&fr[r >> 2];
      const float* f1 = (const float*)&fi[r >> 2];
      v2f v; v.x = f0[r & 3]; v.y = f1[r & 3];
      *(v2f*)(C0 + (bo ^ AT.t[0].so[r])) = v;
    }
    __syncthreads();
    #pragma unroll
    for (int r = 0; r < 16; ++r)
      z[r] = *(const v2f*)(C0 + (bn ^ AT.t[0].rn[r]));
  }

  layer<0>(z, tid, ang, Lb, C0, C1);
  layer<1>(z, tid, ang, Lb, C0, C1);
  layer<2>(z, tid, ang, Lb, C0, C1);

  // ---- final: stash (T=36) -> canonical read -> coalesced float4 stores ----
  {
    unsigned acc = 0;
    #pragma unroll
    for (int i = 0; i < 8; ++i)
      acc ^= (unsigned)(-((tid >> i) & 1)) & AT.t[36].pk[i];
    const unsigned bo = (acc & 0xfffu) << 3;
    const unsigned bn = ((acc >> 16) & 0xfffu) << 3;
    char* buf = AT.buf[36] ? C1 : C0;
    #pragma unroll
    for (int r = 0; r < 16; ++r)
      *(v2f*)(buf + (bo ^ AT.t[36].so[r])) = z[r];
    __syncthreads();
    v2f* o2 = (v2f*)out + (size_t)b * DIM + (tid << 4);
    #pragma unroll
    for (int r = 0; r < 16; r += 2) {
      v2f v0 = *(const v2f*)(buf + (bn ^ AT.t[36].rn[r]));
      v2f v1 = *(const v2f*)(buf + (bn ^ AT.t[36].rn[r + 1]));
      float4 w; w.x = v0.x; w.y = v0.y; w.z = v1.x; w.w = v1.y;
      *(float4*)(o2 + r) = w;
    }
  }
}

extern "C" void kernel_launch(void* const* d_in, const int* in_sizes, int n_in,
                              void* d_out, int out_size, void* d_ws, size_t ws_size,
                              hipStream_t stream) {
  const float* sre    = (const float*)d_in[0];
  const float* sim    = (const float*)d_in[1];
  const float* params = (const float*)d_in[2];
  float* out          = (float*)d_out;

  const int B = in_sizes[0] / DIM;   // 128
  ansatz_kernel<<<B, BLK, 0, stream>>>(sre, sim, params, out);
}

// Round 6
// 84.112 us; speedup vs baseline: 1.2661x; 1.0779x over previous
//
#include <hip/hip_runtime.h>
#include <math.h>

#define DIM  4096
#define BLK  512            // 8 waves; 8 amplitudes (v2f) per thread; 2 waves/SIMD
#define NPAR 144

typedef float v2f __attribute__((ext_vector_type(2)));

// ---------------------------------------------------------------------------
// 12 canonical state bits per phase: 3 register bits (reg[j]), 3 wave bits
// (tid bits 6,7,8), 6 lane bits (tid 0..5). Gates act on register-local bits.
// Restage between epochs: wave-pinned runs -> wave-local (no barrier).
// Layer = 12 epochs (3-bit windows, RYs merged into the CRX chain windows).
// ---------------------------------------------------------------------------
struct Ph { int reg[3]; int wav[3]; };
struct TMap { unsigned pk[9]; unsigned short so[8]; unsigned short rn[8]; };

constexpr int REGS[12][3] = {
  {11,0,1},{1,2,3},{3,4,5},{5,6,7},{7,8,9},{9,10,11},
  {11,0,1},{9,10,11},{7,8,9},{5,6,7},{3,4,5},{1,2,3}};

constexpr Ph phaseAt(int i) {         // i = 0..37; 0/37 = global pseudo-phase
  Ph p = {};
  if (i == 0 || i == 37) {
    p.reg[0]=0; p.reg[1]=1; p.reg[2]=2;
    p.wav[0]=9; p.wav[1]=10; p.wav[2]=11;
    return p;
  }
  int e = (i - 1) % 12;
  for (int j = 0; j < 3; ++j) p.reg[j] = REGS[e][j];
  bool A = (e <= 2) || (e >= 10);     // pin {6,7,8} else {2,3,4}
  p.wav[0] = A ? 6 : 2; p.wav[1] = A ? 7 : 3; p.wav[2] = A ? 8 : 4;
  return p;
}
constexpr bool inArr(const int* a, int n, int b) {
  for (int i = 0; i < n; ++i) if (a[i] == b) return true;
  return false;
}
constexpr bool isLoc(int t) {         // transition t: phase t -> t+1
  if (t == 0 || t == 36) return false;
  Ph a = phaseAt(t), b = phaseAt(t + 1);
  return a.wav[0]==b.wav[0] && a.wav[1]==b.wav[1] && a.wav[2]==b.wav[2];
}
constexpr int bufIdx(int t) {         // alternate cross buffers C0/C1
  int k = 0;
  for (int u = 0; u <= t; ++u) if (!isLoc(u)) ++k;
  return (k + 1) & 1;
}

struct BuildOut { TMap m; bool ok; };

// GF(2)-linear canonical->slot map per transition. Slot bits 0..3 (bank-pair
// bits of an 8B access) built from lane bits of both endpoint phases; for
// local transitions the 3 wave bits occupy slot bits 9..11 -> each wave owns
// a private 4 KB region (no inter-wave sync needed). Invertibility checked.
constexpr BuildOut buildT(Ph o, Ph n, bool local) {
  BuildOut R = {};
  R.ok = true;
  bool lo[12] = {}, ln[12] = {};
  for (int b = 0; b < 12; ++b) {
    lo[b] = !inArr(o.reg,3,b) && !inArr(o.wav,3,b);
    ln[b] = !inArr(n.reg,3,b) && !inArr(n.wav,3,b);
  }
  int col[12] = {};
  bool uo[12] = {}, un[12] = {}, inBank[12] = {}, pairA[12] = {};
  int row = 0;
  for (int b = 0; b < 12 && row < 4; ++b)
    if (lo[b] && ln[b]) { col[b] |= 1 << row; uo[b]=un[b]=true; inBank[b]=true; ++row; }
  while (row < 4) {
    int a = -1, c = -1;
    for (int b = 0; b < 12; ++b) if (lo[b] && !uo[b]) { a = b; break; }
    for (int b = 0; b < 12; ++b) if (ln[b] && !un[b]) { c = b; break; }
    if (a < 0 || c < 0 || a == c) { R.ok = false; return R; }
    col[a] |= 1 << row; col[c] |= 1 << row;
    uo[a]=true; un[c]=true; inBank[a]=true; inBank[c]=true; pairA[a]=true;
    ++row;
  }
  bool idset[12] = {};
  int nid = 0;
  for (int b = 0; b < 12; ++b) { idset[b] = !inBank[b] || pairA[b]; if (idset[b]) ++nid; }
  if (nid != 8) { R.ok = false; return R; }
  if (local) {
    for (int i = 0; i < 3; ++i) {
      if (!idset[o.wav[i]]) { R.ok = false; return R; }
      col[o.wav[i]] |= 1 << (9 + i);
      idset[o.wav[i]] = false;
    }
    int rr = 4;
    for (int b = 0; b < 12; ++b) if (idset[b]) { col[b] |= 1 << rr; ++rr; }
    if (rr != 9) { R.ok = false; return R; }
  } else {
    int rr = 4;
    for (int b = 0; b < 12; ++b) if (idset[b]) { col[b] |= 1 << rr; ++rr; }
    if (rr != 12) { R.ok = false; return R; }
  }
  {                                     // rank-12 invertibility over GF(2)
    int pv[12] = {}, pb[12] = {};
    int nr = 0;
    for (int b = 0; b < 12; ++b) {
      int v = col[b];
      for (int k = 0; k < nr; ++k) if (v & pb[k]) v ^= pv[k];
      if (v) { pb[nr] = v & (-v); pv[nr] = v; ++nr; }
    }
    if (nr != 12) { R.ok = false; return R; }
  }
  int Lo[6] = {}, Ln[6] = {};
  int i0 = 0, i1 = 0;
  for (int b = 0; b < 12; ++b) { if (lo[b]) Lo[i0++] = b; if (ln[b]) Ln[i1++] = b; }
  for (int i = 0; i < 9; ++i) {
    unsigned po = (i < 6) ? (unsigned)col[Lo[i]] : (unsigned)col[o.wav[i-6]];
    unsigned pn = (i < 6) ? (unsigned)col[Ln[i]] : (unsigned)col[n.wav[i-6]];
    R.m.pk[i] = po | (pn << 16);
  }
  for (int r = 0; r < 8; ++r) {
    int s = 0, t2 = 0;
    for (int j = 0; j < 3; ++j)
      if ((r >> j) & 1) { s ^= col[o.reg[j]]; t2 ^= col[n.reg[j]]; }
    R.m.so[r] = (unsigned short)(s * 8);
    R.m.rn[r] = (unsigned short)(t2 * 8);
  }
  return R;
}

struct AllT { TMap t[37]; bool loc[37]; int buf[37]; bool ok; };
constexpr AllT buildAll() {
  AllT A = {};
  A.ok = true;
  for (int t = 0; t < 37; ++t) {
    BuildOut b = buildT(phaseAt(t), phaseAt(t + 1), isLoc(t));
    A.t[t] = b.m;
    A.ok = A.ok && b.ok;
    A.loc[t] = isLoc(t);
    A.buf[t] = bufIdx(t);
  }
  return A;
}
constexpr AllT AT = buildAll();
static_assert(AT.ok, "slot-map construction failed");

// ---------------- gates on the 8-amplitude register file --------------------
template<int J>
__device__ __forceinline__ void ry8(v2f (&z)[8], v2f a) {
  const float c = a.x, s = a.y;
  #pragma unroll
  for (int p = 0; p < 4; ++p) {
    const int r0 = ((p & ~((1 << J) - 1)) << 1) | (p & ((1 << J) - 1));
    const int r1 = r0 | (1 << J);
    v2f u = z[r0], v = z[r1];
    z[r0] = c * u - s * v;
    z[r1] = s * u + c * v;
  }
}
// CRX, off-diagonal -i*s (validated R1-R5)
template<int JC, int JT>
__device__ __forceinline__ void crx8(v2f (&z)[8], v2f a) {
  const float c = a.x, s = a.y;
  constexpr int MC = 1 << JC, MT = 1 << JT;
  constexpr int mlo = MC < MT ? MC : MT;
  constexpr int mhi = MC < MT ? MT : MC;
  #pragma unroll
  for (int p = 0; p < 2; ++p) {
    int q = ((p & ~(mlo - 1)) << 1) | (p & (mlo - 1));
    q = ((q & ~(mhi - 1)) << 1) | (q & (mhi - 1));
    const int r0 = q | MC, r1 = r0 | MT;
    v2f u = z[r0], v = z[r1];
    v2f n0, n1;
    n0.x = c * u.x + s * v.y;
    n0.y = c * u.y - s * v.x;
    n1.x = c * v.x + s * u.y;
    n1.y = c * v.y - s * u.x;
    z[r0] = n0; z[r1] = n1;
  }
}

// Epoch gate lists (canonical orders re-derived from the reference; RY0 rides
// ahead of the g1 chain, RY2 ahead of the g3 chain, all merges commutation-legal).
template<int E>
__device__ __forceinline__ void gates(v2f (&z)[8], const v2f* ang, int base) {
  auto A = [&](int k) { return ang[base + k]; };
  if constexpr (E == 0)      { ry8<0>(z,A(0));  ry8<1>(z,A(11)); ry8<2>(z,A(10));
                               crx8<1,0>(z,A(12)); crx8<2,1>(z,A(13)); }
  else if constexpr (E == 1) { ry8<1>(z,A(9));  ry8<2>(z,A(8));
                               crx8<1,0>(z,A(14)); crx8<2,1>(z,A(15)); }
  else if constexpr (E == 2) { ry8<1>(z,A(7));  ry8<2>(z,A(6));
                               crx8<1,0>(z,A(16)); crx8<2,1>(z,A(17)); }
  else if constexpr (E == 3) { ry8<1>(z,A(5));  ry8<2>(z,A(4));
                               crx8<1,0>(z,A(18)); crx8<2,1>(z,A(19)); }
  else if constexpr (E == 4) { ry8<1>(z,A(3));  ry8<2>(z,A(2));
                               crx8<1,0>(z,A(20)); crx8<2,1>(z,A(21)); }
  else if constexpr (E == 5) { ry8<1>(z,A(1));
                               crx8<1,0>(z,A(22)); crx8<2,1>(z,A(23)); }
  else if constexpr (E == 6) { ry8<0>(z,A(24)); ry8<1>(z,A(35)); ry8<2>(z,A(34));
                               crx8<1,2>(z,A(36)); crx8<0,1>(z,A(37)); }
  else if constexpr (E == 7) { ry8<0>(z,A(26)); ry8<1>(z,A(25));
                               crx8<1,2>(z,A(38)); crx8<0,1>(z,A(39)); }
  else if constexpr (E == 8) { ry8<0>(z,A(28)); ry8<1>(z,A(27));
                               crx8<1,2>(z,A(40)); crx8<0,1>(z,A(41)); }
  else if constexpr (E == 9) { ry8<0>(z,A(30)); ry8<1>(z,A(29));
                               crx8<1,2>(z,A(42)); crx8<0,1>(z,A(43)); }
  else if constexpr (E == 10){ ry8<0>(z,A(32)); ry8<1>(z,A(31));
                               crx8<1,2>(z,A(44)); crx8<0,1>(z,A(45)); }
  else                       { ry8<1>(z,A(33));
                               crx8<1,2>(z,A(46)); crx8<0,1>(z,A(47)); }
}

template<int T>
__device__ __forceinline__ void restage(v2f (&z)[8], int tid, char* Lb, char* C0, char* C1) {
  constexpr bool LOC = AT.loc[T];
  char* buf = LOC ? Lb : (AT.buf[T] ? C1 : C0);
  unsigned acc = 0;
  #pragma unroll
  for (int i = 0; i < 9; ++i)
    acc ^= (unsigned)(-((tid >> i) & 1)) & AT.t[T].pk[i];
  const unsigned bo = (acc & 0xfffu) << 3;
  const unsigned bn = ((acc >> 16) & 0xfffu) << 3;
  #pragma unroll
  for (int r = 0; r < 8; ++r)
    *(v2f*)(buf + (bo ^ AT.t[T].so[r])) = z[r];
  if (LOC) { asm volatile("s_waitcnt lgkmcnt(0)" ::: "memory"); }
  else     { __syncthreads(); }
  #pragma unroll
  for (int r = 0; r < 8; ++r)
    z[r] = *(const v2f*)(buf + (bn ^ AT.t[T].rn[r]));
}

template<int L>
__device__ __forceinline__ void layer(v2f (&z)[8], int tid, const v2f* ang,
                                      char* Lb, char* C0, char* C1) {
  const int base = 48 * L;
  gates<0>(z, ang, base);  restage<12*L + 1>(z, tid, Lb, C0, C1);
  gates<1>(z, ang, base);  restage<12*L + 2>(z, tid, Lb, C0, C1);
  gates<2>(z, ang, base);  restage<12*L + 3>(z, tid, Lb, C0, C1);
  gates<3>(z, ang, base);  restage<12*L + 4>(z, tid, Lb, C0, C1);
  gates<4>(z, ang, base);  restage<12*L + 5>(z, tid, Lb, C0, C1);
  gates<5>(z, ang, base);  restage<12*L + 6>(z, tid, Lb, C0, C1);
  gates<6>(z, ang, base);  restage<12*L + 7>(z, tid, Lb, C0, C1);
  gates<7>(z, ang, base);  restage<12*L + 8>(z, tid, Lb, C0, C1);
  gates<8>(z, ang, base);  restage<12*L + 9>(z, tid, Lb, C0, C1);
  gates<9>(z, ang, base);  restage<12*L + 10>(z, tid, Lb, C0, C1);
  gates<10>(z, ang, base); restage<12*L + 11>(z, tid, Lb, C0, C1);
  gates<11>(z, ang, base);
  if constexpr (L < 2) restage<12*L + 12>(z, tid, Lb, C0, C1);
}

__global__ __launch_bounds__(BLK) void ansatz_kernel(
    const float* __restrict__ sre, const float* __restrict__ sim,
    const float* __restrict__ params, float* __restrict__ out) {

  __shared__ v2f C0s[DIM], C1s[DIM], Ls[DIM];   // 3 x 32 KB
  __shared__ v2f ang[NPAR];

  const int b = blockIdx.x, tid = threadIdx.x;
  char* C0 = (char*)C0s;
  char* C1 = (char*)C1s;
  char* Lb = (char*)Ls;

  if (tid < NPAR) {
    float s, c;
    sincosf(0.5f * params[b * NPAR + tid], &s, &c);
    v2f a; a.x = c; a.y = s;
    ang[tid] = a;
  }

  v2f z[8];
  // ---- init: 8 consecutive amps per thread -> stash into C0 (T=0) ----
  {
    const float4* pr = (const float4*)(sre + b * DIM + (tid << 3));
    const float4* pi = (const float4*)(sim + b * DIM + (tid << 3));
    float4 fr[2], fi[2];
    fr[0] = pr[0]; fr[1] = pr[1];
    fi[0] = pi[0]; fi[1] = pi[1];
    unsigned acc = 0;
    #pragma unroll
    for (int i = 0; i < 9; ++i)
      acc ^= (unsigned)(-((tid >> i) & 1)) & AT.t[0].pk[i];
    const unsigned bo = (acc & 0xfffu) << 3;
    const unsigned bn = ((acc >> 16) & 0xfffu) << 3;
    #pragma unroll
    for (int r = 0; r < 8; ++r) {
      const float* f0 = (const float*)&fr[r >> 2];
      const float* f1 = (const float*)&fi[r >> 2];
      v2f v; v.x = f0[r & 3]; v.y = f1[r & 3];
      *(v2f*)(C0 + (bo ^ AT.t[0].so[r])) = v;
    }
    __syncthreads();
    #pragma unroll
    for (int r = 0; r < 8; ++r)
      z[r] = *(const v2f*)(C0 + (bn ^ AT.t[0].rn[r]));
  }

  layer<0>(z, tid, ang, Lb, C0, C1);
  layer<1>(z, tid, ang, Lb, C0, C1);
  layer<2>(z, tid, ang, Lb, C0, C1);

  // ---- final: stash (T=36, cross) -> canonical read -> float4 stores ----
  {
    unsigned acc = 0;
    #pragma unroll
    for (int i = 0; i < 9; ++i)
      acc ^= (unsigned)(-((tid >> i) & 1)) & AT.t[36].pk[i];
    const unsigned bo = (acc & 0xfffu) << 3;
    const unsigned bn = ((acc >> 16) & 0xfffu) << 3;
    char* buf = AT.buf[36] ? C1 : C0;
    #pragma unroll
    for (int r = 0; r < 8; ++r)
      *(v2f*)(buf + (bo ^ AT.t[36].so[r])) = z[r];
    __syncthreads();
    v2f* o2 = (v2f*)out + (size_t)b * DIM + (tid << 3);
    #pragma unroll
    for (int r = 0; r < 8; r += 2) {
      v2f v0 = *(const v2f*)(buf + (bn ^ AT.t[36].rn[r]));
      v2f v1 = *(const v2f*)(buf + (bn ^ AT.t[36].rn[r + 1]));
      float4 w; w.x = v0.x; w.y = v0.y; w.z = v1.x; w.w = v1.y;
      *(float4*)(o2 + r) = w;
    }
  }
}

extern "C" void kernel_launch(void* const* d_in, const int* in_sizes, int n_in,
                              void* d_out, int out_size, void* d_ws, size_t ws_size,
                              hipStream_t stream) {
  const float* sre    = (const float*)d_in[0];
  const float* sim    = (const float*)d_in[1];
  const float* params = (const float*)d_in[2];
  float* out          = (float*)d_out;

  const int B = in_sizes[0] / DIM;   // 128
  ansatz_kernel<<<B, BLK, 0, stream>>>(sre, sim, params, out);
}

// Round 7
// 80.740 us; speedup vs baseline: 1.3190x; 1.0418x over previous
//
#include <hip/hip_runtime.h>
#include <math.h>

#define DIM  4096
#define BLK  512            // 8 waves; 8 amplitudes (v2f) per thread; 2 waves/SIMD
#define NPAR 144

typedef float v2f __attribute__((ext_vector_type(2)));

// ---------------------------------------------------------------------------
// 12 canonical state bits per phase: 3 register bits, 3 wave bits (tid 6..8),
// 6 lane bits (tid 0..5). Gates act on register-local bits. Restage between
// epochs; wave-pinned runs -> wave-local (no barrier, no waitcnt: LDS is
// in-order per wave). Every transition's windows share one register bit ->
// slot bit 0 -> full b128 stash AND unstash.
// ---------------------------------------------------------------------------
struct Ph { int reg[3]; int wav[3]; };
struct TMap { unsigned pk[9]; unsigned short so[8]; unsigned short rn[8]; };

constexpr int REGS[12][3] = {
  {11,0,1},{1,2,3},{3,4,5},{5,6,7},{7,8,9},{9,10,11},
  {11,0,1},{9,10,11},{7,8,9},{5,6,7},{3,4,5},{1,2,3}};

constexpr Ph phaseAt(int i) {         // i = 0..37; 0/37 = global pseudo-phase
  Ph p = {};
  if (i == 0 || i == 37) {
    p.reg[0]=0; p.reg[1]=1; p.reg[2]=2;
    p.wav[0]=9; p.wav[1]=10; p.wav[2]=11;
    return p;
  }
  int e = (i - 1) % 12;
  for (int j = 0; j < 3; ++j) p.reg[j] = REGS[e][j];
  bool A = (e <= 2) || (e >= 10);     // pin {6,7,8} else {2,3,4}
  p.wav[0] = A ? 6 : 2; p.wav[1] = A ? 7 : 3; p.wav[2] = A ? 8 : 4;
  return p;
}
constexpr bool inArr(const int* a, int n, int b) {
  for (int i = 0; i < n; ++i) if (a[i] == b) return true;
  return false;
}
constexpr int idxOf3(const int* a, int v) {
  for (int j = 0; j < 3; ++j) if (a[j] == v) return j;
  return -1;
}
constexpr bool isLoc(int t) {
  if (t == 0 || t == 36) return false;
  Ph a = phaseAt(t), b = phaseAt(t + 1);
  return a.wav[0]==b.wav[0] && a.wav[1]==b.wav[1] && a.wav[2]==b.wav[2];
}
constexpr int bufIdx(int t) {
  int k = 0;
  for (int u = 0; u <= t; ++u) if (!isLoc(u)) ++k;
  return (k + 1) & 1;
}
constexpr int sharedBit(Ph o, Ph n) {
  for (int j = 0; j < 3; ++j) if (inArr(n.reg, 3, o.reg[j])) return o.reg[j];
  return -1;
}

struct BuildOut { TMap m; int js, jn; bool ok; };

// GF(2)-linear canonical->slot map. Row 0 = shared reg bit (b128 pairing on
// both sides). Rows 1..3 from lane bits of both phases (b128 bank pattern =
// stride-1 equivalent). Local: wave bits -> rows 9..11 (private 4 KB/wave).
constexpr BuildOut buildT(Ph o, Ph n, bool local) {
  BuildOut R = {};
  R.ok = true;
  int s = sharedBit(o, n);
  if (s < 0) { R.ok = false; return R; }
  R.js = idxOf3(o.reg, s);
  R.jn = idxOf3(n.reg, s);
  if (R.js < 0 || R.jn < 0) { R.ok = false; return R; }
  bool lo[12] = {}, ln[12] = {};
  for (int b = 0; b < 12; ++b) {
    lo[b] = !inArr(o.reg,3,b) && !inArr(o.wav,3,b);
    ln[b] = !inArr(n.reg,3,b) && !inArr(n.wav,3,b);
  }
  int col[12] = {};
  bool uo[12] = {}, un[12] = {}, consumed[12] = {};
  col[s] = 1; consumed[s] = true;
  int row = 1;
  for (int b = 0; b < 12 && row < 4; ++b)
    if (lo[b] && ln[b]) { col[b] = 1 << row; uo[b]=un[b]=true; consumed[b]=true; ++row; }
  while (row < 4) {
    int a = -1, c = -1;
    for (int b = 0; b < 12; ++b) if (lo[b] && !uo[b] && !consumed[b]) { a = b; break; }
    for (int b = 0; b < 12; ++b) if (ln[b] && !un[b] && !consumed[b] && b != a) { c = b; break; }
    if (a < 0 || c < 0) { R.ok = false; return R; }
    col[a] |= 1 << row; col[c] |= 1 << row;
    uo[a]=true; un[c]=true; consumed[c]=true;     // a still needs an identity row
    ++row;
  }
  if (local) {
    for (int i = 0; i < 3; ++i) {
      if (consumed[o.wav[i]]) { R.ok = false; return R; }
      col[o.wav[i]] |= 1 << (9 + i);
      consumed[o.wav[i]] = true;
    }
    int rr = 4;
    for (int b = 0; b < 12; ++b) if (!consumed[b]) { col[b] |= 1 << rr; ++rr; }
    if (rr != 9) { R.ok = false; return R; }
  } else {
    int rr = 4;
    for (int b = 0; b < 12; ++b) if (!consumed[b]) { col[b] |= 1 << rr; ++rr; }
    if (rr != 12) { R.ok = false; return R; }
  }
  {                                     // rank-12 invertibility over GF(2)
    int pv[12] = {}, pb[12] = {};
    int nr = 0;
    for (int b = 0; b < 12; ++b) {
      int v = col[b];
      for (int k = 0; k < nr; ++k) if (v & pb[k]) v ^= pv[k];
      if (v) { pb[nr] = v & (-v); pv[nr] = v; ++nr; }
    }
    if (nr != 12) { R.ok = false; return R; }
  }
  int Lo[6] = {}, Ln[6] = {};
  int i0 = 0, i1 = 0;
  for (int b = 0; b < 12; ++b) { if (lo[b]) Lo[i0++] = b; if (ln[b]) Ln[i1++] = b; }
  if (i0 != 6 || i1 != 6) { R.ok = false; return R; }
  for (int i = 0; i < 9; ++i) {
    unsigned po = (i < 6) ? (unsigned)col[Lo[i]] : (unsigned)col[o.wav[i-6]];
    unsigned pn = (i < 6) ? (unsigned)col[Ln[i]] : (unsigned)col[n.wav[i-6]];
    R.m.pk[i] = po | (pn << 16);
  }
  for (int r = 0; r < 8; ++r) {
    int a = 0, c = 0;
    for (int j = 0; j < 3; ++j)
      if ((r >> j) & 1) { a ^= col[o.reg[j]]; c ^= col[n.reg[j]]; }
    R.m.so[r] = (unsigned short)(a * 8);
    R.m.rn[r] = (unsigned short)(c * 8);
  }
  return R;
}

struct AllT { TMap t[37]; bool loc[37]; int buf[37]; int js[37]; int jn[37]; bool ok; };
constexpr AllT buildAll() {
  AllT A = {};
  A.ok = true;
  for (int t = 0; t < 37; ++t) {
    BuildOut b = buildT(phaseAt(t), phaseAt(t + 1), isLoc(t));
    A.t[t] = b.m;
    A.ok = A.ok && b.ok;
    A.loc[t] = isLoc(t);
    A.buf[t] = bufIdx(t);
    A.js[t] = b.js;
    A.jn[t] = b.jn;
  }
  return A;
}
constexpr AllT AT = buildAll();
static_assert(AT.ok, "slot-map construction failed");

// ---------------- gates on the 8-amplitude register file --------------------
template<int J>
__device__ __forceinline__ void ry8(v2f (&z)[8], v2f a) {
  const float c = a.x, s = a.y;
  #pragma unroll
  for (int p = 0; p < 4; ++p) {
    const int r0 = ((p & ~((1 << J) - 1)) << 1) | (p & ((1 << J) - 1));
    const int r1 = r0 | (1 << J);
    v2f u = z[r0], v = z[r1];
    z[r0] = c * u - s * v;
    z[r1] = s * u + c * v;
  }
}
// CRX, off-diagonal -i*s (validated R1-R6)
template<int JC, int JT>
__device__ __forceinline__ void crx8(v2f (&z)[8], v2f a) {
  const float c = a.x, s = a.y;
  constexpr int MC = 1 << JC, MT = 1 << JT;
  constexpr int mlo = MC < MT ? MC : MT;
  constexpr int mhi = MC < MT ? MT : MC;
  #pragma unroll
  for (int p = 0; p < 2; ++p) {
    int q = ((p & ~(mlo - 1)) << 1) | (p & (mlo - 1));
    q = ((q & ~(mhi - 1)) << 1) | (q & (mhi - 1));
    const int r0 = q | MC, r1 = r0 | MT;
    v2f u = z[r0], v = z[r1];
    v2f n0, n1;
    n0.x = c * u.x + s * v.y;
    n0.y = c * u.y - s * v.x;
    n1.x = c * v.x + s * u.y;
    n1.y = c * v.y - s * u.x;
    z[r0] = n0; z[r1] = n1;
  }
}

// Epoch gate lists — identical to the R6-validated schedule.
template<int E>
__device__ __forceinline__ void gates(v2f (&z)[8], const v2f* ang, int base) {
  auto A = [&](int k) { return ang[base + k]; };
  if constexpr (E == 0)      { ry8<0>(z,A(0));  ry8<1>(z,A(11)); ry8<2>(z,A(10));
                               crx8<1,0>(z,A(12)); crx8<2,1>(z,A(13)); }
  else if constexpr (E == 1) { ry8<1>(z,A(9));  ry8<2>(z,A(8));
                               crx8<1,0>(z,A(14)); crx8<2,1>(z,A(15)); }
  else if constexpr (E == 2) { ry8<1>(z,A(7));  ry8<2>(z,A(6));
                               crx8<1,0>(z,A(16)); crx8<2,1>(z,A(17)); }
  else if constexpr (E == 3) { ry8<1>(z,A(5));  ry8<2>(z,A(4));
                               crx8<1,0>(z,A(18)); crx8<2,1>(z,A(19)); }
  else if constexpr (E == 4) { ry8<1>(z,A(3));  ry8<2>(z,A(2));
                               crx8<1,0>(z,A(20)); crx8<2,1>(z,A(21)); }
  else if constexpr (E == 5) { ry8<1>(z,A(1));
                               crx8<1,0>(z,A(22)); crx8<2,1>(z,A(23)); }
  else if constexpr (E == 6) { ry8<0>(z,A(24)); ry8<1>(z,A(35)); ry8<2>(z,A(34));
                               crx8<1,2>(z,A(36)); crx8<0,1>(z,A(37)); }
  else if constexpr (E == 7) { ry8<0>(z,A(26)); ry8<1>(z,A(25));
                               crx8<1,2>(z,A(38)); crx8<0,1>(z,A(39)); }
  else if constexpr (E == 8) { ry8<0>(z,A(28)); ry8<1>(z,A(27));
                               crx8<1,2>(z,A(40)); crx8<0,1>(z,A(41)); }
  else if constexpr (E == 9) { ry8<0>(z,A(30)); ry8<1>(z,A(29));
                               crx8<1,2>(z,A(42)); crx8<0,1>(z,A(43)); }
  else if constexpr (E == 10){ ry8<0>(z,A(32)); ry8<1>(z,A(31));
                               crx8<1,2>(z,A(44)); crx8<0,1>(z,A(45)); }
  else                       { ry8<1>(z,A(33));
                               crx8<1,2>(z,A(46)); crx8<0,1>(z,A(47)); }
}

template<int T>
__device__ __forceinline__ void restage(v2f (&z)[8], int tid, char* Lb, char* C0, char* C1) {
  constexpr bool LOC = AT.loc[T];
  constexpr int JS = AT.js[T], JN = AT.jn[T];
  char* buf = LOC ? Lb : (AT.buf[T] ? C1 : C0);
  unsigned acc = 0;
  #pragma unroll
  for (int i = 0; i < 9; ++i)
    acc ^= (unsigned)(-((tid >> i) & 1)) & AT.t[T].pk[i];
  const unsigned bo = (acc & 0xfffu) << 3;
  const unsigned bn = ((acc >> 16) & 0xfffu) << 3;
  // stash: 4 x ds_write_b128, pairing regs over the shared bit (slot bit 0)
  #pragma unroll
  for (int r = 0; r < 8; ++r) {
    if (r & (1 << JS)) continue;
    v2f z0 = z[r], z1 = z[r | (1 << JS)];
    float4 w; w.x = z0.x; w.y = z0.y; w.z = z1.x; w.w = z1.y;
    *(float4*)(buf + (bo ^ AT.t[T].so[r])) = w;
  }
  if (LOC) {
    // LDS ops of one wave are serviced in program order; the unstash reads
    // queue behind the stash writes in the LDS pipe — no waitcnt needed.
    asm volatile("" ::: "memory");
  } else {
    __syncthreads();
  }
  // unstash: 4 x ds_read_b128
  #pragma unroll
  for (int r = 0; r < 8; ++r) {
    if (r & (1 << JN)) continue;
    float4 w = *(const float4*)(buf + (bn ^ AT.t[T].rn[r]));
    v2f z0, z1;
    z0.x = w.x; z0.y = w.y;
    z1.x = w.z; z1.y = w.w;
    z[r] = z0;
    z[r | (1 << JN)] = z1;
  }
}

template<int L>
__device__ __forceinline__ void layer(v2f (&z)[8], int tid, const v2f* ang,
                                      char* Lb, char* C0, char* C1) {
  const int base = 48 * L;
  gates<0>(z, ang, base);  restage<12*L + 1>(z, tid, Lb, C0, C1);
  gates<1>(z, ang, base);  restage<12*L + 2>(z, tid, Lb, C0, C1);
  gates<2>(z, ang, base);  restage<12*L + 3>(z, tid, Lb, C0, C1);
  gates<3>(z, ang, base);  restage<12*L + 4>(z, tid, Lb, C0, C1);
  gates<4>(z, ang, base);  restage<12*L + 5>(z, tid, Lb, C0, C1);
  gates<5>(z, ang, base);  restage<12*L + 6>(z, tid, Lb, C0, C1);
  gates<6>(z, ang, base);  restage<12*L + 7>(z, tid, Lb, C0, C1);
  gates<7>(z, ang, base);  restage<12*L + 8>(z, tid, Lb, C0, C1);
  gates<8>(z, ang, base);  restage<12*L + 9>(z, tid, Lb, C0, C1);
  gates<9>(z, ang, base);  restage<12*L + 10>(z, tid, Lb, C0, C1);
  gates<10>(z, ang, base); restage<12*L + 11>(z, tid, Lb, C0, C1);
  gates<11>(z, ang, base);
  if constexpr (L < 2) restage<12*L + 12>(z, tid, Lb, C0, C1);
}

__global__ __launch_bounds__(BLK) void ansatz_kernel(
    const float* __restrict__ sre, const float* __restrict__ sim,
    const float* __restrict__ params, float* __restrict__ out) {

  __shared__ alignas(16) v2f C0s[DIM], C1s[DIM], Ls[DIM];   // 3 x 32 KB
  __shared__ v2f ang[NPAR];

  const int b = blockIdx.x, tid = threadIdx.x;
  char* C0 = (char*)C0s;
  char* C1 = (char*)C1s;
  char* Lb = (char*)Ls;

  if (tid < NPAR) {
    float s, c;
    sincosf(0.5f * params[b * NPAR + tid], &s, &c);
    v2f a; a.x = c; a.y = s;
    ang[tid] = a;
  }

  v2f z[8];
  // init: 8 consecutive amps per thread via float4 loads -> restage<0> (cross)
  {
    const float4* pr = (const float4*)(sre + b * DIM + (tid << 3));
    const float4* pi = (const float4*)(sim + b * DIM + (tid << 3));
    float4 fr0 = pr[0], fr1 = pr[1];
    float4 fi0 = pi[0], fi1 = pi[1];
    z[0].x = fr0.x; z[0].y = fi0.x;
    z[1].x = fr0.y; z[1].y = fi0.y;
    z[2].x = fr0.z; z[2].y = fi0.z;
    z[3].x = fr0.w; z[3].y = fi0.w;
    z[4].x = fr1.x; z[4].y = fi1.x;
    z[5].x = fr1.y; z[5].y = fi1.y;
    z[6].x = fr1.z; z[6].y = fi1.z;
    z[7].x = fr1.w; z[7].y = fi1.w;
    restage<0>(z, tid, Lb, C0, C1);
  }

  layer<0>(z, tid, ang, Lb, C0, C1);
  layer<1>(z, tid, ang, Lb, C0, C1);
  layer<2>(z, tid, ang, Lb, C0, C1);

  // final: restage<36> back to global layout -> coalesced float4 stores
  restage<36>(z, tid, Lb, C0, C1);
  v2f* o2 = (v2f*)out + (size_t)b * DIM + (tid << 3);
  #pragma unroll
  for (int r = 0; r < 8; r += 2) {
    float4 w;
    w.x = z[r].x;     w.y = z[r].y;
    w.z = z[r + 1].x; w.w = z[r + 1].y;
    *(float4*)(o2 + r) = w;
  }
}

extern "C" void kernel_launch(void* const* d_in, const int* in_sizes, int n_in,
                              void* d_out, int out_size, void* d_ws, size_t ws_size,
                              hipStream_t stream) {
  const float* sre    = (const float*)d_in[0];
  const float* sim    = (const float*)d_in[1];
  const float* params = (const float*)d_in[2];
  float* out          = (float*)d_out;

  const int B = in_sizes[0] / DIM;   // 128
  ansatz_kernel<<<B, BLK, 0, stream>>>(sre, sim, params, out);
}